// Round 4
// baseline (10817.429 us; speedup 1.0000x reference)
//
#include <hip/hip_runtime.h>
#include <cstdint>
#include <cstddef>

// ---------------------------------------------------------------------------
// IntentClassifier on MI355X.
//   dense(1024->1024) folded into layer0 Wi (Wc = W_reg@Wi0)
//   R7: x@Wi hoisted out of the recurrence, chunked (TC=32) into a 25 MB
//     union region. Per layer: 16x { xp_gemm(chunk) ; recur_fused(32 steps) }.
//   R8: barrier restructured — master/gen hop removed; each wg's wave0
//     directly polls the 96 arrival slots of ITS direction (forward and
//     backward recurrences are independent, so per-dir barriers suffice).
//     c-state registerized across each chunk (global only at boundaries).
//     Dead-batch freeze store dropped (frozen h is never consumed).
//     Attention GEMM skips tiles entirely past nf[b].
//   R9: identical resubmit of R8 (previous round died to a container/infra
//     failure before reaching the GPU; sync audit found no hang path).
//   2x BiLSTM (H=768): persistent grid-barrier kernel, h@Wh with
//     register-pinned split Wh (hi+lo) and bf16 (hi-only) h.
//   h-state loads = batched global_load_dwordx4 sc0 sc1, one vmcnt per step;
//   barrier: slot stores + direct per-dir poll (absolute t across launches).
// ---------------------------------------------------------------------------

typedef __attribute__((ext_vector_type(8))) short s8v;   // 8 x bf16
typedef __attribute__((ext_vector_type(4))) short s4v;
typedef __attribute__((ext_vector_type(4))) float f4v;
typedef __attribute__((ext_vector_type(4))) int   v4i;

#define MFMA16(a,b,c) __builtin_amdgcn_mfma_f32_16x16x32_bf16((a),(b),(c),0,0,0)

#define NB   64
#define NT   512
#define MTOT (NB*NT)     // 32768 rows
#define TC   32          // recurrence chunk (timesteps per xp buffer refill)

__device__ __forceinline__ ushort f2bf(float x){
  uint32_t u = __float_as_uint(x);
  uint32_t r = (u + 0x7FFFu + ((u >> 16) & 1u)) >> 16;   // RNE
  return (ushort)r;
}
__device__ __forceinline__ float bf2f(ushort h){
  return __uint_as_float(((uint32_t)h) << 16);
}
__device__ __forceinline__ float fsig(float x){
  x = fminf(30.f, fmaxf(-30.f, x));
  return 1.f / (1.f + __expf(-x));
}
__device__ __forceinline__ float ftanh(float x){
  x = fminf(15.f, fmaxf(-15.f, x));
  float e = __expf(2.f * x);
  return (e - 1.f) / (e + 1.f);
}
__device__ __forceinline__ s8v as8(v4i x){ union{v4i a; s8v b;} u; u.a=x; return u.b; }

// ------------------------- weight prep kernels -----------------------------
__global__ void transpose_split_kernel(const float* __restrict__ B,
                                       ushort* __restrict__ Th,
                                       ushort* __restrict__ Tl,
                                       int K, int N){
  __shared__ float tile[64][65];
  int k0 = blockIdx.x * 64, n0 = blockIdx.y * 64;
  for (int i = threadIdx.x; i < 4096; i += 256){
    int r = i >> 6, c = i & 63;
    tile[r][c] = B[(size_t)(k0 + r) * N + (n0 + c)];
  }
  __syncthreads();
  for (int i = threadIdx.x; i < 4096; i += 256){
    int nr = i >> 6, kc = i & 63;
    float x = tile[kc][nr];
    ushort h = f2bf(x);
    ushort lo = f2bf(x - bf2f(h));
    size_t o = (size_t)(n0 + nr) * K + (k0 + kc);
    Th[o] = h; Tl[o] = lo;
  }
}

// Wh (768,3072) fp32 -> fragment-packed bf16 hi/lo: [wgd(96)][nt(2)][kt(24)][lane(64)][j(8)]
__global__ void whpack_kernel(const float* __restrict__ Wh,
                              ushort* __restrict__ Ph, ushort* __restrict__ Pl){
  int idx = blockIdx.x * 256 + threadIdx.x;     // 2,359,296 total
  int j    = idx & 7;
  int lane = (idx >> 3) & 63;
  int kt   = (idx >> 9) % 24;
  int rest = idx / (24 * 512);                  // wgd*2 + nt
  int nt   = rest & 1;
  int wgd  = rest >> 1;
  int c    = lane & 15;
  int gate = nt * 2 + (c >> 3);
  int q    = wgd * 8 + (c & 7);
  int k    = kt * 32 + (lane >> 4) * 8 + j;
  float x = Wh[(size_t)k * 3072 + gate * 768 + q];
  ushort h = f2bf(x);
  Ph[idx] = h;
  Pl[idx] = f2bf(x - bf2f(h));
}

// W (K,3072) fp32 -> packed bf16 [wgd(96)][n(32)][k(K)], col(n)=(n>>3)*768+wgd*8+(n&7)
__global__ void pack_wi_kernel(const float* __restrict__ W,
                               ushort* __restrict__ dst, int K){
  int total = 96 * 32 * K;
  for (int idx = blockIdx.x * 256 + threadIdx.x; idx < total; idx += gridDim.x * 256){
    int k = idx % K;
    int rest = idx / K;            // wgd*32 + n
    int n = rest & 31, wgd = rest >> 5;
    float x = W[(size_t)k * 3072 + (n >> 3) * 768 + wgd * 8 + (n & 7)];
    dst[idx] = f2bf(x);
  }
}

// bc[d][c] = b_d[c] + sum_k breg[k]*W_d[k,c]   (W=nullptr -> plain copy)
__global__ void bias_comb_kernel(const float* __restrict__ bf, const float* __restrict__ bb,
                                 const float* __restrict__ Wf, const float* __restrict__ Wb,
                                 const float* __restrict__ breg, int Kb,
                                 float* __restrict__ bc){
  int c = blockIdx.x * 256 + threadIdx.x;   // < 3072
  int d = blockIdx.y;
  const float* b = d ? bb : bf;
  const float* W = d ? Wb : Wf;
  float acc = b[c];
  if (W){
    for (int k = 0; k < Kb; k++) acc += breg[k] * W[(size_t)k * 3072 + c];
  }
  bc[d * 3072 + c] = acc;
}

__global__ void zero_kernel(uint32_t* __restrict__ p, int n){
  for (int i = blockIdx.x * 256 + threadIdx.x; i < n; i += gridDim.x * 256)
    p[i] = 0u;
}

// ------------------------- split-bf16 GEMM ---------------------------------
// MODE 0: C = A@B + bias (fp32 out).   MODE 2: scores[row] += sum_col tanh(C)*We[col]
// ABF 0: A fp32 (split in-kernel, 3-pass).  ABF 1: A bf16 (2-pass)
// MODE 2: rows are (b,t) = m/512, m%512; 128-row tiles lie within one b.
//   Tiles with t0 >= nf[b] are fully masked downstream -> early exit.
template<int MODE, int ABF>
__global__ __launch_bounds__(256, 2) void gemm_kernel(
    const void* __restrict__ Araw, const ushort* __restrict__ Bh,
    const ushort* __restrict__ Bl, const float* __restrict__ bias,
    float* __restrict__ outF,
    const float* __restrict__ We, float* __restrict__ scores,
    const int* __restrict__ nf,
    int M, int N, int K)
{
  __shared__ short lA_h[128*40], lA_l[128*40], lB_h[128*40], lB_l[128*40];
  int tid = threadIdx.x, l = tid & 63, w = tid >> 6;
  int wr = w >> 1, wc = w & 1;
  int nbM = M >> 7;
  int mblk = blockIdx.x % nbM, nblk = blockIdx.x / nbM;
  if (MODE == 2){
    int b = mblk >> 2, t0 = (mblk & 3) * 128;
    if (nf[b] <= t0) return;       // whole tile past sequence end
  }
  f4v acc[4][4];
  for (int i=0;i<4;i++) for (int j=0;j<4;j++) acc[i][j] = (f4v){0.f,0.f,0.f,0.f};
  int nk = K >> 5;
  const ushort* Bhb = Bh + (size_t)nblk*128*K;
  const ushort* Blb = Bl + (size_t)nblk*128*K;
  int mrow = l & 15, koff = (l >> 4) * 8;
  for (int kt = 0; kt < nk; kt++){
    if (ABF == 0){   // fp32 A -> split hi/lo
      const float* Ab = (const float*)Araw + (size_t)mblk*128*K;
      int c4 = (l & 7) * 4;
      #pragma unroll
      for (int i=0;i<4;i++){
        int r = (w*4 + i)*8 + (l >> 3);
        const float* p = Ab + (size_t)r*K + kt*32 + c4;
        float4 v = *(const float4*)p;
        float xs[4] = {v.x, v.y, v.z, v.w};
        s4v hv, lv;
        #pragma unroll
        for (int j=0;j<4;j++){
          ushort hh = f2bf(xs[j]);
          hv[j] = (short)hh;
          lv[j] = (short)f2bf(xs[j] - bf2f(hh));
        }
        *(s4v*)&lA_h[r*40 + c4] = hv;
        *(s4v*)&lA_l[r*40 + c4] = lv;
      }
    } else {         // bf16 A
      const ushort* Ab = (const ushort*)Araw + (size_t)mblk*128*K;
      int k8 = (l & 3) * 8;
      #pragma unroll
      for (int i=0;i<2;i++){
        int r = (w*2 + i)*16 + (l >> 2);
        *(s8v*)&lA_h[r*40 + k8] = *(const s8v*)(Ab + (size_t)r*K + kt*32 + k8);
      }
    }
    {
      int k8 = (l & 3) * 8;
      #pragma unroll
      for (int i=0;i<2;i++){
        int r = (w*2 + i)*16 + (l >> 2);
        size_t o = (size_t)r*K + kt*32 + k8;
        *(s8v*)&lB_h[r*40 + k8] = *(const s8v*)(Bhb + o);
        *(s8v*)&lB_l[r*40 + k8] = *(const s8v*)(Blb + o);
      }
    }
    __syncthreads();
    s8v ah[4], al[4], bh[4], bl[4];
    #pragma unroll
    for (int mt=0;mt<4;mt++){
      int base = (wr*64 + mt*16 + mrow)*40 + koff;
      ah[mt] = *(s8v*)&lA_h[base];
      if (ABF == 0) al[mt] = *(s8v*)&lA_l[base];
    }
    #pragma unroll
    for (int nt=0;nt<4;nt++){
      int base = (wc*64 + nt*16 + mrow)*40 + koff;
      bh[nt] = *(s8v*)&lB_h[base];
      bl[nt] = *(s8v*)&lB_l[base];
    }
    #pragma unroll
    for (int mt=0;mt<4;mt++)
      #pragma unroll
      for (int nt=0;nt<4;nt++){
        acc[mt][nt] = MFMA16(ah[mt], bh[nt], acc[mt][nt]);
        acc[mt][nt] = MFMA16(ah[mt], bl[nt], acc[mt][nt]);
        if (ABF == 0) acc[mt][nt] = MFMA16(al[mt], bh[nt], acc[mt][nt]);
      }
    __syncthreads();
  }
  // epilogue. C/D layout: col = lane&15, row = (lane>>4)*4 + r
  if (MODE == 2){
    float pre[4][4];
    #pragma unroll
    for (int mt=0;mt<4;mt++) for (int r=0;r<4;r++) pre[mt][r] = 0.f;
    #pragma unroll
    for (int nt=0;nt<4;nt++){
      int colg = nblk*128 + wc*64 + nt*16 + (l & 15);
      float we = We[colg];
      #pragma unroll
      for (int mt=0;mt<4;mt++)
        #pragma unroll
        for (int r=0;r<4;r++)
          pre[mt][r] += ftanh(acc[mt][nt][r]) * we;
    }
    #pragma unroll
    for (int mt=0;mt<4;mt++)
      #pragma unroll
      for (int r=0;r<4;r++){
        float v = pre[mt][r];
        v += __shfl_xor(v, 1); v += __shfl_xor(v, 2);
        v += __shfl_xor(v, 4); v += __shfl_xor(v, 8);
        if ((l & 15) == 0){
          int rowg = mblk*128 + wr*64 + mt*16 + (l>>4)*4 + r;
          atomicAdd(scores + rowg, v);
        }
      }
  } else {
    #pragma unroll
    for (int mt=0;mt<4;mt++)
      #pragma unroll
      for (int nt=0;nt<4;nt++){
        int rowg0 = mblk*128 + wr*64 + mt*16 + (l>>4)*4;
        int colg  = nblk*128 + wc*64 + nt*16 + (l & 15);
        float bv = bias ? bias[colg] : 0.f;
        #pragma unroll
        for (int r=0;r<4;r++){
          float v = acc[mt][nt][r] + bv;
          outF[(size_t)(rowg0 + r)*N + colg] = v;
        }
      }
  }
}

// ------------------------- chunked xp precompute GEMM ----------------------
// Time-ordered xp chunk: out[(tc*64 + b)*6144 + pc] (bf16) =
//   A[b, r(dir,b,t0+tc)] @ wip-row pc,  pc = dir*3072 + wgd*32 + n,
//   r = dir ? nf[b]-1-t : t (clamped; clamped rows feed finished batches,
//   whose gate outputs are discarded).  dir = (nblk >= 24).
// grid = 16 mblk x 48 nblk (M_chunk = TC*64 = 2048 rows).
// ABF 2: A fp32 (hi-only convert).  ABF 1: A bf16.
template<int ABF>
__global__ __launch_bounds__(256, 2) void xp_gemm(
    const void* __restrict__ Araw, const ushort* __restrict__ Bp,
    const int* __restrict__ nf, int t0,
    ushort* __restrict__ outB, int K)
{
  __shared__ short lA[128*40], lB[128*40];
  __shared__ int srow[128];
  int tid = threadIdx.x, l = tid & 63, w = tid >> 6;
  int wr = w >> 1, wc = w & 1;
  int mblk = blockIdx.x & 15;
  int nblk = blockIdx.x >> 4;          // [0,48)
  int dir = (nblk >= 24) ? 1 : 0;
  if (tid < 128){
    int m = mblk*128 + tid;
    int b = m & 63, tc = m >> 6;
    int t = t0 + tc;
    int r = dir ? (nf[b] - 1 - t) : t;
    r = max(0, min(511, r));
    srow[tid] = b*512 + r;
  }
  __syncthreads();
  f4v acc[4][4];
  for (int i=0;i<4;i++) for (int j=0;j<4;j++) acc[i][j] = (f4v){0.f,0.f,0.f,0.f};
  int nk = K >> 5;
  const ushort* Bb = Bp + (size_t)nblk*128*K;
  int mrow = l & 15, koff = (l >> 4) * 8;
  for (int kt = 0; kt < nk; kt++){
    if (ABF == 2){   // fp32 A -> hi-only bf16
      const float* Af = (const float*)Araw;
      int c4 = (l & 7) * 4;
      #pragma unroll
      for (int i=0;i<4;i++){
        int r = (w*4 + i)*8 + (l >> 3);
        const float* p = Af + (size_t)srow[r]*K + kt*32 + c4;
        float4 v = *(const float4*)p;
        s4v hv;
        hv[0] = (short)f2bf(v.x); hv[1] = (short)f2bf(v.y);
        hv[2] = (short)f2bf(v.z); hv[3] = (short)f2bf(v.w);
        *(s4v*)&lA[r*40 + c4] = hv;
      }
    } else {         // bf16 A
      const ushort* Au = (const ushort*)Araw;
      int k8 = (l & 3) * 8;
      #pragma unroll
      for (int i=0;i<2;i++){
        int r = (w*2 + i)*16 + (l >> 2);
        *(s8v*)&lA[r*40 + k8] = *(const s8v*)(Au + (size_t)srow[r]*K + kt*32 + k8);
      }
    }
    {
      int k8 = (l & 3) * 8;
      #pragma unroll
      for (int i=0;i<2;i++){
        int r = (w*2 + i)*16 + (l >> 2);
        *(s8v*)&lB[r*40 + k8] = *(const s8v*)(Bb + (size_t)r*K + kt*32 + k8);
      }
    }
    __syncthreads();
    s8v ah[4], bh4[4];
    #pragma unroll
    for (int mt=0;mt<4;mt++) ah[mt] = *(s8v*)&lA[(wr*64 + mt*16 + mrow)*40 + koff];
    #pragma unroll
    for (int nt=0;nt<4;nt++) bh4[nt] = *(s8v*)&lB[(wc*64 + nt*16 + mrow)*40 + koff];
    #pragma unroll
    for (int mt=0;mt<4;mt++)
      #pragma unroll
      for (int nt=0;nt<4;nt++)
        acc[mt][nt] = MFMA16(ah[mt], bh4[nt], acc[mt][nt]);
    __syncthreads();
  }
  #pragma unroll
  for (int mt=0;mt<4;mt++)
    #pragma unroll
    for (int nt=0;nt<4;nt++){
      int rowg0 = mblk*128 + wr*64 + mt*16 + (l>>4)*4;
      int colg  = nblk*128 + wc*64 + nt*16 + (l & 15);
      #pragma unroll
      for (int r=0;r<4;r++)
        outB[(size_t)(rowg0 + r)*6144 + colg] = f2bf(acc[mt][nt][r]);
    }
}

// ------------------------- fused persistent BiLSTM -------------------------
// grid = 192 x 256. dir = bx&1, wgd = bx>>1 owns 8 h-cols (32 z-cols).
// Runs timesteps [t0, tEnd) of the global recurrence; state (h ping-pong,
// c at chunk boundaries, per-dir arrival slots) lives in global memory and
// continues across chunk launches (slots hold ABSOLUTE completed-step count).
// R8 barrier: arrive = slot store barr[dir*96+wgd]; wait = wave0 of every wg
// polls all 96 slots of its own dir (no master, no gen flag). Forward and
// backward recurrences never exchange data, so per-dir barriers suffice.
// Release chain: producer drains vmcnt(0) on sc0 sc1 h-stores (acked at the
// coherence point) BEFORE issuing its slot store, so a consumer observing
// slot >= t also observes the h values of step t-1.
// h hi-only (bf16); Wh split hi/lo in registers (2-pass h@Wh).
// c-state in registers within a chunk (each thread owns its 2 cells).
__global__ __launch_bounds__(256, 1) void recur_fused(
    const ushort* __restrict__ xp,
    const ushort* __restrict__ whfh, const ushort* __restrict__ whfl,
    const ushort* __restrict__ whbh, const ushort* __restrict__ whbl,
    const float* __restrict__ bias2, ushort* __restrict__ enc,
    const int* __restrict__ nf, ushort* __restrict__ hstate,
    float* __restrict__ cstate, int* __restrict__ barr,
    int t0, int tEnd)
{
  __shared__ float zlds[9216];        // [w][mt][nt][col16][row pad18]
  __shared__ float bcs[32];
  __shared__ int nfs[64];
  const int tid = threadIdx.x, l = tid & 63, w = tid >> 6;
  const int dir = blockIdx.x & 1, wgd = blockIdx.x >> 1, wq0 = wgd * 8;

  if (tid < 64) nfs[tid] = nf[tid];
  if (tid < 32) bcs[tid] = bias2[dir*3072 + (tid>>3)*768 + wq0 + (tid&7)];
  __syncthreads();
  // gate cells: thread owns 2 ADJACENT cols (q0=2*qp, q0+1) of batch gb
  const int gb = tid >> 2, qp = tid & 3, q0 = qp*2;
  const int gL = nfs[gb];
  const int ghidx = gb*768 + wq0 + q0;          // dword-aligned (q0 even)
  float* cst = cstate + dir * 49152;
  float creg[2];                                // registerized c across chunk
  creg[0] = cst[ghidx];
  creg[1] = cst[ghidx + 1];

  const ushort* wph = dir ? whbh : whfh;
  const ushort* wpl = dir ? whbl : whfl;
  s8v whh[2][6], whl[2][6];
  #pragma unroll
  for (int nt=0;nt<2;nt++)
    for (int i=0;i<6;i++){
      size_t o = ((size_t)((wgd*2 + nt)*24 + (w*6 + i)) * 64 + l) * 8;
      whh[nt][i] = *(const s8v*)(wph + o);
      whl[nt][i] = *(const s8v*)(wpl + o);
    }

  // h fragment byte offsets (step-invariant): frag(i,mt) at hoff[mt] + i*64
  uint32_t hoff[4];
  #pragma unroll
  for (int mt=0;mt<4;mt++)
    hoff[mt] = (uint32_t)(((mt*16 + (l & 15))*768 + w*192 + ((l>>4)*8)) * 2);
  // hstate hi-only: [dir(2)][phase(2)][49152]
  uint64_t hb0 = (uint64_t)(uintptr_t)(hstate + (size_t)(dir*2 + 0)*49152);
  uint64_t hb1 = (uint64_t)(uintptr_t)(hstate + (size_t)(dir*2 + 1)*49152);

  // xp base for this thread's gate batch/cols (chunk row stride 64*6144)
  const ushort* xcb = xp + (size_t)gb*6144 + (size_t)(dir*3072 + wgd*32);

  const int slot = dir*96 + wgd;   // this wg's arrival slot
  const int sb   = dir*96;         // base of this dir's 96 slots

  for (int t = t0; t < tEnd; t++){
    if (t > 0 && w == 0){
      // direct per-dir barrier: wave0 polls all 96 slots of this dir
      for (;;){
        int v0 = __hip_atomic_load(barr + sb + l, __ATOMIC_RELAXED, __HIP_MEMORY_SCOPE_AGENT);
        int v1 = (l < 32)
          ? __hip_atomic_load(barr + sb + 64 + l, __ATOMIC_RELAXED, __HIP_MEMORY_SCOPE_AGENT)
          : 0x7fffffff;
        if (__all(min(v0, v1) >= t)) break;
        __builtin_amdgcn_s_sleep(1);
      }
    }
    __syncthreads();
    const int p = t & 1;
    const uint64_t rb = p ? hb1 : hb0;
    const uint64_t wb = p ? hb0 : hb1;

    // ---- batched coherent h-loads: 24 x 16B via v[addr] form ----
    v4i F[4][6];
    #pragma unroll
    for (int mt=0; mt<4; mt++){
      uint64_t amt = rb + hoff[mt];
      asm volatile(
        "global_load_dwordx4 %0, %6, off sc0 sc1\n\t"
        "global_load_dwordx4 %1, %6, off offset:64 sc0 sc1\n\t"
        "global_load_dwordx4 %2, %6, off offset:128 sc0 sc1\n\t"
        "global_load_dwordx4 %3, %6, off offset:192 sc0 sc1\n\t"
        "global_load_dwordx4 %4, %6, off offset:256 sc0 sc1\n\t"
        "global_load_dwordx4 %5, %6, off offset:320 sc0 sc1"
        : "=&v"(F[mt][0]),"=&v"(F[mt][1]),"=&v"(F[mt][2]),
          "=&v"(F[mt][3]),"=&v"(F[mt][4]),"=&v"(F[mt][5])
        : "v"(amt)
        : "memory");
    }
    // ---- xp loads for this step (read-once cached loads); covered by the
    //      same vmcnt(0) below ----
    const ushort* xrow = xcb + (size_t)(t - t0) * (64*6144);
    uint32_t xq[4];
    #pragma unroll
    for (int g=0; g<4; g++) xq[g] = *(const uint32_t*)(xrow + g*8 + q0);

    asm volatile("s_waitcnt vmcnt(0)"
      : "+v"(F[0][0]),"+v"(F[0][1]),"+v"(F[0][2]),"+v"(F[0][3]),"+v"(F[0][4]),"+v"(F[0][5]),
        "+v"(F[1][0]),"+v"(F[1][1]),"+v"(F[1][2]),"+v"(F[1][3]),"+v"(F[1][4]),"+v"(F[1][5]),
        "+v"(F[2][0]),"+v"(F[2][1]),"+v"(F[2][2]),"+v"(F[2][3]),"+v"(F[2][4]),"+v"(F[2][5]),
        "+v"(F[3][0]),"+v"(F[3][1]),"+v"(F[3][2]),"+v"(F[3][3]),"+v"(F[3][4]),"+v"(F[3][5])
      :
      : "memory");

    f4v acc[4][2];
    #pragma unroll
    for (int mt=0;mt<4;mt++){
      acc[mt][0] = (f4v){0.f,0.f,0.f,0.f};
      acc[mt][1] = (f4v){0.f,0.f,0.f,0.f};
    }
    #pragma unroll
    for (int i=0;i<6;i++){
      #pragma unroll
      for (int mt=0;mt<4;mt++){
        s8v ahh = as8(F[mt][i]);
        acc[mt][0] = MFMA16(ahh, whh[0][i], acc[mt][0]);
        acc[mt][0] = MFMA16(ahh, whl[0][i], acc[mt][0]);
        acc[mt][1] = MFMA16(ahh, whh[1][i], acc[mt][1]);
        acc[mt][1] = MFMA16(ahh, whl[1][i], acc[mt][1]);
      }
    }
    #pragma unroll
    for (int mt=0;mt<4;mt++)
      #pragma unroll
      for (int nt=0;nt<2;nt++){
        int base = (((w*4 + mt)*2 + nt)*16 + (l & 15))*18 + (l>>4)*4;
        zlds[base+0] = acc[mt][nt][0];
        zlds[base+1] = acc[mt][nt][1];
        zlds[base+2] = acc[mt][nt][2];
        zlds[base+3] = acc[mt][nt][3];
      }
    __syncthreads();
    { // gates: 2 adjacent cols per thread
      if (t < gL){
        int mt = gb >> 4, row = gb & 15;
        float nhv[2];
        #pragma unroll
        for (int e=0;e<2;e++){
          int q = q0 + e;
          float zg4[4];
          #pragma unroll
          for (int g=0; g<4; g++){
            int nt = g >> 1, c = (g & 1)*8 + q;
            int zb = ((mt*2 + nt)*16 + c)*18 + row;
            zg4[g] = zlds[zb] + zlds[zb+2304] + zlds[zb+4608] + zlds[zb+6912]
                   + bcs[g*8 + q] + bf2f((ushort)(xq[g] >> (16*e)));
          }
          float nc = fsig(zg4[1])*creg[e] + fsig(zg4[0])*ftanh(zg4[2]);
          float nh = fsig(zg4[3])*ftanh(nc);
          creg[e] = nc;
          nhv[e] = nh;
        }
        ushort h0h = f2bf(nhv[0]), h1h = f2bf(nhv[1]);
        uint32_t pk = (uint32_t)h0h | ((uint32_t)h1h << 16);
        uint64_t sa = wb + (uint32_t)(ghidx * 2);
        asm volatile("global_store_dword %0, %1, off sc0 sc1"
                     :: "v"(sa), "v"(pk) : "memory");
        int r = dir ? (gL - 1 - t) : t;
        *(uint32_t*)&enc[((size_t)gb*512 + r)*1536 + dir*768 + wq0 + q0] = pk;
      }
      // NOTE: frozen (t >= gL) batches' h is never consumed downstream —
      // their z rows are discarded and enc is only written for t < gL —
      // so no freeze store is needed.
    }
    asm volatile("s_waitcnt vmcnt(0)" ::: "memory");  // h stores ack'd at IC
    __syncthreads();
    if (t < 511 && tid == 0)   // arrive: plain coherent store to private slot
      __hip_atomic_store(barr + slot, t + 1, __ATOMIC_RELAXED, __HIP_MEMORY_SCOPE_AGENT);
  }
  // write back registerized c for the next chunk
  cst[ghidx]     = creg[0];
  cst[ghidx + 1] = creg[1];
}

// ------------------------- attention tail ----------------------------------
__global__ void softmax_kernel(const float* __restrict__ scores,
                               const int* __restrict__ nf,
                               float* __restrict__ attn){
  __shared__ float red[4], red2[4];
  int b = blockIdx.x, tid = threadIdx.x;
  int L = nf[b];
  float v0 = (tid       < L) ? scores[b*512 + tid]       : -1e30f;
  float v1 = (tid + 256 < L) ? scores[b*512 + tid + 256] : -1e30f;
  float mx = fmaxf(v0, v1);
  for (int m=1; m<64; m<<=1) mx = fmaxf(mx, __shfl_xor(mx, m));
  if ((tid & 63) == 0) red[tid >> 6] = mx;
  __syncthreads();
  mx = fmaxf(fmaxf(red[0], red[1]), fmaxf(red[2], red[3]));
  float e0 = (tid       < L) ? __expf(v0 - mx) : 0.f;
  float e1 = (tid + 256 < L) ? __expf(v1 - mx) : 0.f;
  float s = e0 + e1;
  for (int m=1; m<64; m<<=1) s += __shfl_xor(s, m);
  if ((tid & 63) == 0) red2[tid >> 6] = s;
  __syncthreads();
  s = red2[0] + red2[1] + red2[2] + red2[3];
  float inv = 1.f / s;
  attn[b*512 + tid]       = e0 * inv;
  attn[b*512 + tid + 256] = e1 * inv;
}

__global__ void context_kernel(const ushort* __restrict__ enc,
                               const float* __restrict__ attn,
                               float* __restrict__ ctx){
  int b = blockIdx.x, tid = threadIdx.x;
  float a6[6] = {0.f,0.f,0.f,0.f,0.f,0.f};
  for (int t=0; t<512; t++){
    float a = attn[b*512 + t];
    if (a != 0.f){
      const ushort* e = enc + ((size_t)b*512 + t)*1536;
      #pragma unroll
      for (int i=0;i<6;i++) a6[i] += a * bf2f(e[tid + i*256]);
    }
  }
  #pragma unroll
  for (int i=0;i<6;i++) ctx[b*1536 + tid + i*256] = a6[i];
}

__global__ void post_kernel(const float* __restrict__ ctx,
                            const float* __restrict__ Wp,
                            const float* __restrict__ bp,
                            float* __restrict__ post){
  int b = blockIdx.x;
  int j = blockIdx.y*256 + threadIdx.x;
  float acc = bp[j];
  const float* c = ctx + b*1536;
  for (int k=0;k<1536;k++) acc += c[k] * Wp[(size_t)k*1536 + j];
  post[b*1536 + j] = acc;
}

__global__ void intents_kernel(const float* __restrict__ post,
                               const float* __restrict__ Wi,
                               const float* __restrict__ bi,
                               float* __restrict__ out){
  int b = blockIdx.x, j = threadIdx.x;
  if (j < 60){
    float acc = bi[j];
    const float* p = post + b*1536;
    for (int k=0;k<1536;k++) acc += p[k] * Wi[k*60 + j];
    out[b*60 + j] = acc;
  }
}

// ------------------------- host side ---------------------------------------
extern "C" void kernel_launch(void* const* d_in, const int* in_sizes, int n_in,
                              void* d_out, int out_size, void* d_ws, size_t ws_size,
                              hipStream_t stream) {
  const float* lat    = (const float*)d_in[0];
  const int*   nf     = (const int*)  d_in[1];
  const float* W_reg  = (const float*)d_in[3];
  const float* b_reg  = (const float*)d_in[4];
  const float* Wi0f   = (const float*)d_in[5];
  const float* Wh0f   = (const float*)d_in[6];
  const float* b0f    = (const float*)d_in[7];
  const float* Wi0b   = (const float*)d_in[8];
  const float* Wh0b   = (const float*)d_in[9];
  const float* b0b    = (const float*)d_in[10];
  const float* Wi1f   = (const float*)d_in[11];
  const float* Wh1f   = (const float*)d_in[12];
  const float* b1f    = (const float*)d_in[13];
  const float* Wi1b   = (const float*)d_in[14];
  const float* Wh1b   = (const float*)d_in[15];
  const float* b1b    = (const float*)d_in[16];
  const float* W_keys = (const float*)d_in[17];
  const float* W_en   = (const float*)d_in[18];
  const float* W_post = (const float*)d_in[19];
  const float* b_post = (const float*)d_in[20];
  const float* W_int  = (const float*)d_in[21];
  const float* b_int  = (const float*)d_in[22];
  float* out = (float*)d_out;

  char* wsp = (char*)d_ws;
  auto alloc = [&](size_t n) -> char* {
    char* p = wsp; wsp += (n + 255) & ~(size_t)255; return p;
  };
  ushort* enc1 = (ushort*)alloc((size_t)MTOT*1536*2);
  ushort* enc2 = (ushort*)alloc((size_t)MTOT*1536*2);
  ushort* wip  = (ushort*)alloc((size_t)2*96*32*1536*2);
  ushort* wh_fh = (ushort*)alloc((size_t)2359296*2);
  ushort* wh_fl = (ushort*)alloc((size_t)2359296*2);
  ushort* wh_bh = (ushort*)alloc((size_t)2359296*2);
  ushort* wh_bl = (ushort*)alloc((size_t)2359296*2);
  float*  bc   = (float*) alloc((size_t)2*3072*4);
  char* state0 = wsp;
  ushort* hstate = (ushort*)alloc((size_t)4*49152*2);   // hi-only: dir x phase
  float*  cstate = (float*) alloc((size_t)2*49152*4);
  int*    barr   = (int*)   alloc(4096);
  size_t state_bytes = (size_t)((char*)wsp - state0);
  // Union region U (25,165,824 B):
  //  - prep phase:   sTh(6291456) | sTl(6291456) | sWc(12582912)
  //  - chunk phase:  xpc = TC*64*6144*2 = 25165824 (whole region)
  //  - attn phase:   sTh | sTl | scores/attn/ctx/postb (13.6 MB total)
  char* U = alloc((size_t)25165824);
  ushort* sTh  = (ushort*)(U);
  ushort* sTl  = (ushort*)(U + 6291456);
  float*  sWc  = (float*) (U + 12582912);
  ushort* xpc  = (ushort*)(U);
  float* scores = (float*)(U + 12582912);
  float* attn   = (float*)(U + 12582912 + 131072);
  float* ctx    = (float*)(U + 12582912 + 262144);
  float* postb  = (float*)(U + 12582912 + 262144 + 393216);
  (void)in_sizes; (void)n_in; (void)out_size; (void)ws_size;

  int state_words = (int)(state_bytes / 4);

  // ---- layer 0 prep: Wc = W_reg @ Wi0{f,b}, pack; Wh0 packs; bias comb ----
  hipLaunchKernelGGL(zero_kernel, dim3(512), dim3(256), 0, stream, (uint32_t*)state0, state_words);
  hipLaunchKernelGGL(transpose_split_kernel, dim3(16,48), dim3(256), 0, stream, Wi0f, sTh, sTl, 1024, 3072);
  hipLaunchKernelGGL((gemm_kernel<0,0>), dim3(8*24), dim3(256), 0, stream,
                     (const void*)W_reg, sTh, sTl, (const float*)nullptr, sWc,
                     (const float*)nullptr, (float*)nullptr, (const int*)nullptr, 1024, 3072, 1024);
  hipLaunchKernelGGL(pack_wi_kernel, dim3(4608), dim3(256), 0, stream, sWc, wip, 1024);
  hipLaunchKernelGGL(transpose_split_kernel, dim3(16,48), dim3(256), 0, stream, Wi0b, sTh, sTl, 1024, 3072);
  hipLaunchKernelGGL((gemm_kernel<0,0>), dim3(8*24), dim3(256), 0, stream,
                     (const void*)W_reg, sTh, sTl, (const float*)nullptr, sWc,
                     (const float*)nullptr, (float*)nullptr, (const int*)nullptr, 1024, 3072, 1024);
  hipLaunchKernelGGL(pack_wi_kernel, dim3(4608), dim3(256), 0, stream, sWc, wip + (size_t)96*32*1024, 1024);
  hipLaunchKernelGGL(whpack_kernel, dim3(9216), dim3(256), 0, stream, Wh0f, wh_fh, wh_fl);
  hipLaunchKernelGGL(whpack_kernel, dim3(9216), dim3(256), 0, stream, Wh0b, wh_bh, wh_bl);
  hipLaunchKernelGGL(bias_comb_kernel, dim3(12,2), dim3(256), 0, stream, b0f, b0b, Wi0f, Wi0b, b_reg, 1024, bc);
  // ---- BiLSTM layer 0: chunked xp (lat fp32, hi-only) + recurrence ----
  for (int c = 0; c < 512/TC; c++){
    int t0 = c*TC;
    hipLaunchKernelGGL((xp_gemm<2>), dim3(16*48), dim3(256), 0, stream,
                       (const void*)lat, wip, nf, t0, xpc, 1024);
    hipLaunchKernelGGL(recur_fused, dim3(192), dim3(256), 0, stream,
                       xpc, wh_fh, wh_fl, wh_bh, wh_bl, bc,
                       enc1, nf, hstate, cstate, barr, t0, t0 + TC);
  }
  // ---- layer 1 prep ----
  hipLaunchKernelGGL(zero_kernel, dim3(512), dim3(256), 0, stream, (uint32_t*)state0, state_words);
  hipLaunchKernelGGL(pack_wi_kernel, dim3(4608), dim3(256), 0, stream, Wi1f, wip, 1536);
  hipLaunchKernelGGL(pack_wi_kernel, dim3(4608), dim3(256), 0, stream, Wi1b, wip + (size_t)96*32*1536, 1536);
  hipLaunchKernelGGL(whpack_kernel, dim3(9216), dim3(256), 0, stream, Wh1f, wh_fh, wh_fl);
  hipLaunchKernelGGL(whpack_kernel, dim3(9216), dim3(256), 0, stream, Wh1b, wh_bh, wh_bl);
  hipLaunchKernelGGL(bias_comb_kernel, dim3(12,2), dim3(256), 0, stream, b1f, b1b,
                     (const float*)nullptr, (const float*)nullptr, b_reg, 0, bc);
  // ---- BiLSTM layer 1: chunked xp (enc1 bf16) + recurrence ----
  for (int c = 0; c < 512/TC; c++){
    int t0 = c*TC;
    hipLaunchKernelGGL((xp_gemm<1>), dim3(16*48), dim3(256), 0, stream,
                       (const void*)enc1, wip, nf, t0, xpc, 1536);
    hipLaunchKernelGGL(recur_fused, dim3(192), dim3(256), 0, stream,
                       xpc, wh_fh, wh_fl, wh_bh, wh_bl, bc,
                       enc2, nf, hstate, cstate, barr, t0, t0 + TC);
  }
  // ---- attention: scores = sum_col tanh(enc2@Wk)*We ----
  hipLaunchKernelGGL(zero_kernel, dim3(128), dim3(256), 0, stream, (uint32_t*)scores, MTOT);
  hipLaunchKernelGGL(transpose_split_kernel, dim3(24,24), dim3(256), 0, stream, W_keys, sTh, sTl, 1536, 1536);
  hipLaunchKernelGGL((gemm_kernel<2,1>), dim3(256*12), dim3(256), 0, stream,
                     (const void*)enc2, sTh, sTl, (const float*)nullptr, (float*)nullptr,
                     W_en, scores, nf, MTOT, 1536, 1536);
  hipLaunchKernelGGL(softmax_kernel, dim3(64), dim3(256), 0, stream, scores, nf, attn);
  hipLaunchKernelGGL(context_kernel, dim3(64), dim3(256), 0, stream, enc2, attn, ctx);
  hipLaunchKernelGGL(post_kernel, dim3(64,6), dim3(256), 0, stream, ctx, W_post, b_post, postb);
  hipLaunchKernelGGL(intents_kernel, dim3(64), dim3(64), 0, stream, postb, W_int, b_int, out);
}

// Round 5
// 9766.745 us; speedup vs baseline: 1.1076x; 1.1076x over previous
//
#include <hip/hip_runtime.h>
#include <cstdint>
#include <cstddef>

// ---------------------------------------------------------------------------
// IntentClassifier on MI355X.
//   dense(1024->1024) folded into layer0 Wi (Wc = W_reg@Wi0)
//   R7: x@Wi hoisted out of the recurrence, chunked (TC=32) into a 25 MB
//     union region. Per layer: 16x { xp_gemm(chunk) ; recur_fused(32 steps) }.
//   R8: c-state registerized across each chunk; dead-batch freeze store
//     dropped; attention GEMM skips tiles past nf[b].
//   R8's direct 96-slot poll REGRESSED (+0.8us/step): 192 wgs hammering the
//     slot lines with agent-scope loads congests the coherence point.
//   R10: barrier = per-DIRECTION master + broadcast gen flag. wg0 (dir0) and
//     wg1 (dir1) each poll their own 96 slots and release their own gen
//     dword on separate cache lines; all other wgs spin on ONE dword.
//   2x BiLSTM (H=768): persistent grid-barrier kernel, h@Wh with
//     register-pinned split Wh (hi+lo) and bf16 (hi-only) h.
//   h-state loads = batched global_load_dwordx4 sc0 sc1, one vmcnt per step;
//   slots/gens hold ABSOLUTE completed-step count (continues across chunks).
// ---------------------------------------------------------------------------

typedef __attribute__((ext_vector_type(8))) short s8v;   // 8 x bf16
typedef __attribute__((ext_vector_type(4))) short s4v;
typedef __attribute__((ext_vector_type(4))) float f4v;
typedef __attribute__((ext_vector_type(4))) int   v4i;

#define MFMA16(a,b,c) __builtin_amdgcn_mfma_f32_16x16x32_bf16((a),(b),(c),0,0,0)

#define NB   64
#define NT   512
#define MTOT (NB*NT)     // 32768 rows
#define TC   32          // recurrence chunk (timesteps per xp buffer refill)

__device__ __forceinline__ ushort f2bf(float x){
  uint32_t u = __float_as_uint(x);
  uint32_t r = (u + 0x7FFFu + ((u >> 16) & 1u)) >> 16;   // RNE
  return (ushort)r;
}
__device__ __forceinline__ float bf2f(ushort h){
  return __uint_as_float(((uint32_t)h) << 16);
}
__device__ __forceinline__ float fsig(float x){
  x = fminf(30.f, fmaxf(-30.f, x));
  return 1.f / (1.f + __expf(-x));
}
__device__ __forceinline__ float ftanh(float x){
  x = fminf(15.f, fmaxf(-15.f, x));
  float e = __expf(2.f * x);
  return (e - 1.f) / (e + 1.f);
}
__device__ __forceinline__ s8v as8(v4i x){ union{v4i a; s8v b;} u; u.a=x; return u.b; }

// ------------------------- weight prep kernels -----------------------------
__global__ void transpose_split_kernel(const float* __restrict__ B,
                                       ushort* __restrict__ Th,
                                       ushort* __restrict__ Tl,
                                       int K, int N){
  __shared__ float tile[64][65];
  int k0 = blockIdx.x * 64, n0 = blockIdx.y * 64;
  for (int i = threadIdx.x; i < 4096; i += 256){
    int r = i >> 6, c = i & 63;
    tile[r][c] = B[(size_t)(k0 + r) * N + (n0 + c)];
  }
  __syncthreads();
  for (int i = threadIdx.x; i < 4096; i += 256){
    int nr = i >> 6, kc = i & 63;
    float x = tile[kc][nr];
    ushort h = f2bf(x);
    ushort lo = f2bf(x - bf2f(h));
    size_t o = (size_t)(n0 + nr) * K + (k0 + kc);
    Th[o] = h; Tl[o] = lo;
  }
}

// Wh (768,3072) fp32 -> fragment-packed bf16 hi/lo: [wgd(96)][nt(2)][kt(24)][lane(64)][j(8)]
__global__ void whpack_kernel(const float* __restrict__ Wh,
                              ushort* __restrict__ Ph, ushort* __restrict__ Pl){
  int idx = blockIdx.x * 256 + threadIdx.x;     // 2,359,296 total
  int j    = idx & 7;
  int lane = (idx >> 3) & 63;
  int kt   = (idx >> 9) % 24;
  int rest = idx / (24 * 512);                  // wgd*2 + nt
  int nt   = rest & 1;
  int wgd  = rest >> 1;
  int c    = lane & 15;
  int gate = nt * 2 + (c >> 3);
  int q    = wgd * 8 + (c & 7);
  int k    = kt * 32 + (lane >> 4) * 8 + j;
  float x = Wh[(size_t)k * 3072 + gate * 768 + q];
  ushort h = f2bf(x);
  Ph[idx] = h;
  Pl[idx] = f2bf(x - bf2f(h));
}

// W (K,3072) fp32 -> packed bf16 [wgd(96)][n(32)][k(K)], col(n)=(n>>3)*768+wgd*8+(n&7)
__global__ void pack_wi_kernel(const float* __restrict__ W,
                               ushort* __restrict__ dst, int K){
  int total = 96 * 32 * K;
  for (int idx = blockIdx.x * 256 + threadIdx.x; idx < total; idx += gridDim.x * 256){
    int k = idx % K;
    int rest = idx / K;            // wgd*32 + n
    int n = rest & 31, wgd = rest >> 5;
    float x = W[(size_t)k * 3072 + (n >> 3) * 768 + wgd * 8 + (n & 7)];
    dst[idx] = f2bf(x);
  }
}

// bc[d][c] = b_d[c] + sum_k breg[k]*W_d[k,c]   (W=nullptr -> plain copy)
__global__ void bias_comb_kernel(const float* __restrict__ bf, const float* __restrict__ bb,
                                 const float* __restrict__ Wf, const float* __restrict__ Wb,
                                 const float* __restrict__ breg, int Kb,
                                 float* __restrict__ bc){
  int c = blockIdx.x * 256 + threadIdx.x;   // < 3072
  int d = blockIdx.y;
  const float* b = d ? bb : bf;
  const float* W = d ? Wb : Wf;
  float acc = b[c];
  if (W){
    for (int k = 0; k < Kb; k++) acc += breg[k] * W[(size_t)k * 3072 + c];
  }
  bc[d * 3072 + c] = acc;
}

__global__ void zero_kernel(uint32_t* __restrict__ p, int n){
  for (int i = blockIdx.x * 256 + threadIdx.x; i < n; i += gridDim.x * 256)
    p[i] = 0u;
}

// ------------------------- split-bf16 GEMM ---------------------------------
// MODE 0: C = A@B + bias (fp32 out).   MODE 2: scores[row] += sum_col tanh(C)*We[col]
// ABF 0: A fp32 (split in-kernel, 3-pass).  ABF 1: A bf16 (2-pass)
// MODE 2: rows are (b,t) = m/512, m%512; 128-row tiles lie within one b.
//   Tiles with t0 >= nf[b] are fully masked downstream -> early exit.
template<int MODE, int ABF>
__global__ __launch_bounds__(256, 2) void gemm_kernel(
    const void* __restrict__ Araw, const ushort* __restrict__ Bh,
    const ushort* __restrict__ Bl, const float* __restrict__ bias,
    float* __restrict__ outF,
    const float* __restrict__ We, float* __restrict__ scores,
    const int* __restrict__ nf,
    int M, int N, int K)
{
  __shared__ short lA_h[128*40], lA_l[128*40], lB_h[128*40], lB_l[128*40];
  int tid = threadIdx.x, l = tid & 63, w = tid >> 6;
  int wr = w >> 1, wc = w & 1;
  int nbM = M >> 7;
  int mblk = blockIdx.x % nbM, nblk = blockIdx.x / nbM;
  if (MODE == 2){
    int b = mblk >> 2, t0 = (mblk & 3) * 128;
    if (nf[b] <= t0) return;       // whole tile past sequence end
  }
  f4v acc[4][4];
  for (int i=0;i<4;i++) for (int j=0;j<4;j++) acc[i][j] = (f4v){0.f,0.f,0.f,0.f};
  int nk = K >> 5;
  const ushort* Bhb = Bh + (size_t)nblk*128*K;
  const ushort* Blb = Bl + (size_t)nblk*128*K;
  int mrow = l & 15, koff = (l >> 4) * 8;
  for (int kt = 0; kt < nk; kt++){
    if (ABF == 0){   // fp32 A -> split hi/lo
      const float* Ab = (const float*)Araw + (size_t)mblk*128*K;
      int c4 = (l & 7) * 4;
      #pragma unroll
      for (int i=0;i<4;i++){
        int r = (w*4 + i)*8 + (l >> 3);
        const float* p = Ab + (size_t)r*K + kt*32 + c4;
        float4 v = *(const float4*)p;
        float xs[4] = {v.x, v.y, v.z, v.w};
        s4v hv, lv;
        #pragma unroll
        for (int j=0;j<4;j++){
          ushort hh = f2bf(xs[j]);
          hv[j] = (short)hh;
          lv[j] = (short)f2bf(xs[j] - bf2f(hh));
        }
        *(s4v*)&lA_h[r*40 + c4] = hv;
        *(s4v*)&lA_l[r*40 + c4] = lv;
      }
    } else {         // bf16 A
      const ushort* Ab = (const ushort*)Araw + (size_t)mblk*128*K;
      int k8 = (l & 3) * 8;
      #pragma unroll
      for (int i=0;i<2;i++){
        int r = (w*2 + i)*16 + (l >> 2);
        *(s8v*)&lA_h[r*40 + k8] = *(const s8v*)(Ab + (size_t)r*K + kt*32 + k8);
      }
    }
    {
      int k8 = (l & 3) * 8;
      #pragma unroll
      for (int i=0;i<2;i++){
        int r = (w*2 + i)*16 + (l >> 2);
        size_t o = (size_t)r*K + kt*32 + k8;
        *(s8v*)&lB_h[r*40 + k8] = *(const s8v*)(Bhb + o);
        *(s8v*)&lB_l[r*40 + k8] = *(const s8v*)(Blb + o);
      }
    }
    __syncthreads();
    s8v ah[4], al[4], bh[4], bl[4];
    #pragma unroll
    for (int mt=0;mt<4;mt++){
      int base = (wr*64 + mt*16 + mrow)*40 + koff;
      ah[mt] = *(s8v*)&lA_h[base];
      if (ABF == 0) al[mt] = *(s8v*)&lA_l[base];
    }
    #pragma unroll
    for (int nt=0;nt<4;nt++){
      int base = (wc*64 + nt*16 + mrow)*40 + koff;
      bh[nt] = *(s8v*)&lB_h[base];
      bl[nt] = *(s8v*)&lB_l[base];
    }
    #pragma unroll
    for (int mt=0;mt<4;mt++)
      #pragma unroll
      for (int nt=0;nt<4;nt++){
        acc[mt][nt] = MFMA16(ah[mt], bh[nt], acc[mt][nt]);
        acc[mt][nt] = MFMA16(ah[mt], bl[nt], acc[mt][nt]);
        if (ABF == 0) acc[mt][nt] = MFMA16(al[mt], bh[nt], acc[mt][nt]);
      }
    __syncthreads();
  }
  // epilogue. C/D layout: col = lane&15, row = (lane>>4)*4 + r
  if (MODE == 2){
    float pre[4][4];
    #pragma unroll
    for (int mt=0;mt<4;mt++) for (int r=0;r<4;r++) pre[mt][r] = 0.f;
    #pragma unroll
    for (int nt=0;nt<4;nt++){
      int colg = nblk*128 + wc*64 + nt*16 + (l & 15);
      float we = We[colg];
      #pragma unroll
      for (int mt=0;mt<4;mt++)
        #pragma unroll
        for (int r=0;r<4;r++)
          pre[mt][r] += ftanh(acc[mt][nt][r]) * we;
    }
    #pragma unroll
    for (int mt=0;mt<4;mt++)
      #pragma unroll
      for (int r=0;r<4;r++){
        float v = pre[mt][r];
        v += __shfl_xor(v, 1); v += __shfl_xor(v, 2);
        v += __shfl_xor(v, 4); v += __shfl_xor(v, 8);
        if ((l & 15) == 0){
          int rowg = mblk*128 + wr*64 + mt*16 + (l>>4)*4 + r;
          atomicAdd(scores + rowg, v);
        }
      }
  } else {
    #pragma unroll
    for (int mt=0;mt<4;mt++)
      #pragma unroll
      for (int nt=0;nt<4;nt++){
        int rowg0 = mblk*128 + wr*64 + mt*16 + (l>>4)*4;
        int colg  = nblk*128 + wc*64 + nt*16 + (l & 15);
        float bv = bias ? bias[colg] : 0.f;
        #pragma unroll
        for (int r=0;r<4;r++){
          float v = acc[mt][nt][r] + bv;
          outF[(size_t)(rowg0 + r)*N + colg] = v;
        }
      }
  }
}

// ------------------------- chunked xp precompute GEMM ----------------------
// Time-ordered xp chunk: out[(tc*64 + b)*6144 + pc] (bf16) =
//   A[b, r(dir,b,t0+tc)] @ wip-row pc,  pc = dir*3072 + wgd*32 + n,
//   r = dir ? nf[b]-1-t : t (clamped; clamped rows feed finished batches,
//   whose gate outputs are discarded).  dir = (nblk >= 24).
// grid = 16 mblk x 48 nblk (M_chunk = TC*64 = 2048 rows).
// ABF 2: A fp32 (hi-only convert).  ABF 1: A bf16.
template<int ABF>
__global__ __launch_bounds__(256, 2) void xp_gemm(
    const void* __restrict__ Araw, const ushort* __restrict__ Bp,
    const int* __restrict__ nf, int t0,
    ushort* __restrict__ outB, int K)
{
  __shared__ short lA[128*40], lB[128*40];
  __shared__ int srow[128];
  int tid = threadIdx.x, l = tid & 63, w = tid >> 6;
  int wr = w >> 1, wc = w & 1;
  int mblk = blockIdx.x & 15;
  int nblk = blockIdx.x >> 4;          // [0,48)
  int dir = (nblk >= 24) ? 1 : 0;
  if (tid < 128){
    int m = mblk*128 + tid;
    int b = m & 63, tc = m >> 6;
    int t = t0 + tc;
    int r = dir ? (nf[b] - 1 - t) : t;
    r = max(0, min(511, r));
    srow[tid] = b*512 + r;
  }
  __syncthreads();
  f4v acc[4][4];
  for (int i=0;i<4;i++) for (int j=0;j<4;j++) acc[i][j] = (f4v){0.f,0.f,0.f,0.f};
  int nk = K >> 5;
  const ushort* Bb = Bp + (size_t)nblk*128*K;
  int mrow = l & 15, koff = (l >> 4) * 8;
  for (int kt = 0; kt < nk; kt++){
    if (ABF == 2){   // fp32 A -> hi-only bf16
      const float* Af = (const float*)Araw;
      int c4 = (l & 7) * 4;
      #pragma unroll
      for (int i=0;i<4;i++){
        int r = (w*4 + i)*8 + (l >> 3);
        const float* p = Af + (size_t)srow[r]*K + kt*32 + c4;
        float4 v = *(const float4*)p;
        s4v hv;
        hv[0] = (short)f2bf(v.x); hv[1] = (short)f2bf(v.y);
        hv[2] = (short)f2bf(v.z); hv[3] = (short)f2bf(v.w);
        *(s4v*)&lA[r*40 + c4] = hv;
      }
    } else {         // bf16 A
      const ushort* Au = (const ushort*)Araw;
      int k8 = (l & 3) * 8;
      #pragma unroll
      for (int i=0;i<2;i++){
        int r = (w*2 + i)*16 + (l >> 2);
        *(s8v*)&lA[r*40 + k8] = *(const s8v*)(Au + (size_t)srow[r]*K + kt*32 + k8);
      }
    }
    {
      int k8 = (l & 3) * 8;
      #pragma unroll
      for (int i=0;i<2;i++){
        int r = (w*2 + i)*16 + (l >> 2);
        *(s8v*)&lB[r*40 + k8] = *(const s8v*)(Bb + (size_t)r*K + kt*32 + k8);
      }
    }
    __syncthreads();
    s8v ah[4], bh4[4];
    #pragma unroll
    for (int mt=0;mt<4;mt++) ah[mt] = *(s8v*)&lA[(wr*64 + mt*16 + mrow)*40 + koff];
    #pragma unroll
    for (int nt=0;nt<4;nt++) bh4[nt] = *(s8v*)&lB[(wc*64 + nt*16 + mrow)*40 + koff];
    #pragma unroll
    for (int mt=0;mt<4;mt++)
      #pragma unroll
      for (int nt=0;nt<4;nt++)
        acc[mt][nt] = MFMA16(ah[mt], bh4[nt], acc[mt][nt]);
    __syncthreads();
  }
  #pragma unroll
  for (int mt=0;mt<4;mt++)
    #pragma unroll
    for (int nt=0;nt<4;nt++){
      int rowg0 = mblk*128 + wr*64 + mt*16 + (l>>4)*4;
      int colg  = nblk*128 + wc*64 + nt*16 + (l & 15);
      #pragma unroll
      for (int r=0;r<4;r++)
        outB[(size_t)(rowg0 + r)*6144 + colg] = f2bf(acc[mt][nt][r]);
    }
}

// ------------------------- fused persistent BiLSTM -------------------------
// grid = 192 x 256. dir = bx&1, wgd = bx>>1 owns 8 h-cols (32 z-cols).
// Runs timesteps [t0, tEnd) of the global recurrence; state (h ping-pong,
// c at chunk boundaries, slots/gens) lives in global memory and continues
// across chunk launches (ABSOLUTE completed-step counts).
// R10 barrier: per-dir master + broadcast gen. Arrive = slot store
// barr[dir*96+wgd]; wg (wgd==0) of each dir polls its 96 slots and releases
// gen at barr[256 + dir*64] (separate cache lines); all other wgs spin on
// that single dword. Release chain: producer drains vmcnt(0) on sc0 sc1
// h-stores BEFORE its slot store, master's gen store follows observing all
// slots, so gen >= t implies h of step t-1 is visible.
// h hi-only (bf16); Wh split hi/lo in registers (2-pass h@Wh).
// c-state in registers within a chunk (each thread owns its 2 cells).
__global__ __launch_bounds__(256, 1) void recur_fused(
    const ushort* __restrict__ xp,
    const ushort* __restrict__ whfh, const ushort* __restrict__ whfl,
    const ushort* __restrict__ whbh, const ushort* __restrict__ whbl,
    const float* __restrict__ bias2, ushort* __restrict__ enc,
    const int* __restrict__ nf, ushort* __restrict__ hstate,
    float* __restrict__ cstate, int* __restrict__ barr,
    int t0, int tEnd)
{
  __shared__ float zlds[9216];        // [w][mt][nt][col16][row pad18]
  __shared__ float bcs[32];
  __shared__ int nfs[64];
  const int tid = threadIdx.x, l = tid & 63, w = tid >> 6;
  const int dir = blockIdx.x & 1, wgd = blockIdx.x >> 1, wq0 = wgd * 8;

  if (tid < 64) nfs[tid] = nf[tid];
  if (tid < 32) bcs[tid] = bias2[dir*3072 + (tid>>3)*768 + wq0 + (tid&7)];
  __syncthreads();
  // gate cells: thread owns 2 ADJACENT cols (q0=2*qp, q0+1) of batch gb
  const int gb = tid >> 2, qp = tid & 3, q0 = qp*2;
  const int gL = nfs[gb];
  const int ghidx = gb*768 + wq0 + q0;          // dword-aligned (q0 even)
  float* cst = cstate + dir * 49152;
  float creg[2];                                // registerized c across chunk
  creg[0] = cst[ghidx];
  creg[1] = cst[ghidx + 1];

  const ushort* wph = dir ? whbh : whfh;
  const ushort* wpl = dir ? whbl : whfl;
  s8v whh[2][6], whl[2][6];
  #pragma unroll
  for (int nt=0;nt<2;nt++)
    for (int i=0;i<6;i++){
      size_t o = ((size_t)((wgd*2 + nt)*24 + (w*6 + i)) * 64 + l) * 8;
      whh[nt][i] = *(const s8v*)(wph + o);
      whl[nt][i] = *(const s8v*)(wpl + o);
    }

  // h fragment byte offsets (step-invariant): frag(i,mt) at hoff[mt] + i*64
  uint32_t hoff[4];
  #pragma unroll
  for (int mt=0;mt<4;mt++)
    hoff[mt] = (uint32_t)(((mt*16 + (l & 15))*768 + w*192 + ((l>>4)*8)) * 2);
  // hstate hi-only: [dir(2)][phase(2)][49152]
  uint64_t hb0 = (uint64_t)(uintptr_t)(hstate + (size_t)(dir*2 + 0)*49152);
  uint64_t hb1 = (uint64_t)(uintptr_t)(hstate + (size_t)(dir*2 + 1)*49152);

  // xp base for this thread's gate batch/cols (chunk row stride 64*6144)
  const ushort* xcb = xp + (size_t)gb*6144 + (size_t)(dir*3072 + wgd*32);

  const int slot = dir*96 + wgd;   // this wg's arrival slot
  const int sb   = dir*96;         // base of this dir's 96 slots
  int* const genp = barr + 256 + dir*64;   // per-dir gen flag, separate lines

  for (int t = t0; t < tEnd; t++){
    if (t > 0 && wgd != 0 && tid == 0){
      // broadcast wait: single dword per dir
      while (__hip_atomic_load(genp, __ATOMIC_RELAXED, __HIP_MEMORY_SCOPE_AGENT) < t)
        __builtin_amdgcn_s_sleep(2);
    }
    __syncthreads();
    const int p = t & 1;
    const uint64_t rb = p ? hb1 : hb0;
    const uint64_t wb = p ? hb0 : hb1;

    // ---- batched coherent h-loads: 24 x 16B via v[addr] form ----
    v4i F[4][6];
    #pragma unroll
    for (int mt=0; mt<4; mt++){
      uint64_t amt = rb + hoff[mt];
      asm volatile(
        "global_load_dwordx4 %0, %6, off sc0 sc1\n\t"
        "global_load_dwordx4 %1, %6, off offset:64 sc0 sc1\n\t"
        "global_load_dwordx4 %2, %6, off offset:128 sc0 sc1\n\t"
        "global_load_dwordx4 %3, %6, off offset:192 sc0 sc1\n\t"
        "global_load_dwordx4 %4, %6, off offset:256 sc0 sc1\n\t"
        "global_load_dwordx4 %5, %6, off offset:320 sc0 sc1"
        : "=&v"(F[mt][0]),"=&v"(F[mt][1]),"=&v"(F[mt][2]),
          "=&v"(F[mt][3]),"=&v"(F[mt][4]),"=&v"(F[mt][5])
        : "v"(amt)
        : "memory");
    }
    // ---- xp loads for this step (read-once cached loads); covered by the
    //      same vmcnt(0) below ----
    const ushort* xrow = xcb + (size_t)(t - t0) * (64*6144);
    uint32_t xq[4];
    #pragma unroll
    for (int g=0; g<4; g++) xq[g] = *(const uint32_t*)(xrow + g*8 + q0);

    asm volatile("s_waitcnt vmcnt(0)"
      : "+v"(F[0][0]),"+v"(F[0][1]),"+v"(F[0][2]),"+v"(F[0][3]),"+v"(F[0][4]),"+v"(F[0][5]),
        "+v"(F[1][0]),"+v"(F[1][1]),"+v"(F[1][2]),"+v"(F[1][3]),"+v"(F[1][4]),"+v"(F[1][5]),
        "+v"(F[2][0]),"+v"(F[2][1]),"+v"(F[2][2]),"+v"(F[2][3]),"+v"(F[2][4]),"+v"(F[2][5]),
        "+v"(F[3][0]),"+v"(F[3][1]),"+v"(F[3][2]),"+v"(F[3][3]),"+v"(F[3][4]),"+v"(F[3][5])
      :
      : "memory");

    f4v acc[4][2];
    #pragma unroll
    for (int mt=0;mt<4;mt++){
      acc[mt][0] = (f4v){0.f,0.f,0.f,0.f};
      acc[mt][1] = (f4v){0.f,0.f,0.f,0.f};
    }
    #pragma unroll
    for (int i=0;i<6;i++){
      #pragma unroll
      for (int mt=0;mt<4;mt++){
        s8v ahh = as8(F[mt][i]);
        acc[mt][0] = MFMA16(ahh, whh[0][i], acc[mt][0]);
        acc[mt][0] = MFMA16(ahh, whl[0][i], acc[mt][0]);
        acc[mt][1] = MFMA16(ahh, whh[1][i], acc[mt][1]);
        acc[mt][1] = MFMA16(ahh, whl[1][i], acc[mt][1]);
      }
    }
    #pragma unroll
    for (int mt=0;mt<4;mt++)
      #pragma unroll
      for (int nt=0;nt<2;nt++){
        int base = (((w*4 + mt)*2 + nt)*16 + (l & 15))*18 + (l>>4)*4;
        zlds[base+0] = acc[mt][nt][0];
        zlds[base+1] = acc[mt][nt][1];
        zlds[base+2] = acc[mt][nt][2];
        zlds[base+3] = acc[mt][nt][3];
      }
    __syncthreads();
    { // gates: 2 adjacent cols per thread
      if (t < gL){
        int mt = gb >> 4, row = gb & 15;
        float nhv[2];
        #pragma unroll
        for (int e=0;e<2;e++){
          int q = q0 + e;
          float zg4[4];
          #pragma unroll
          for (int g=0; g<4; g++){
            int nt = g >> 1, c = (g & 1)*8 + q;
            int zb = ((mt*2 + nt)*16 + c)*18 + row;
            zg4[g] = zlds[zb] + zlds[zb+2304] + zlds[zb+4608] + zlds[zb+6912]
                   + bcs[g*8 + q] + bf2f((ushort)(xq[g] >> (16*e)));
          }
          float nc = fsig(zg4[1])*creg[e] + fsig(zg4[0])*ftanh(zg4[2]);
          float nh = fsig(zg4[3])*ftanh(nc);
          creg[e] = nc;
          nhv[e] = nh;
        }
        ushort h0h = f2bf(nhv[0]), h1h = f2bf(nhv[1]);
        uint32_t pk = (uint32_t)h0h | ((uint32_t)h1h << 16);
        uint64_t sa = wb + (uint32_t)(ghidx * 2);
        asm volatile("global_store_dword %0, %1, off sc0 sc1"
                     :: "v"(sa), "v"(pk) : "memory");
        int r = dir ? (gL - 1 - t) : t;
        *(uint32_t*)&enc[((size_t)gb*512 + r)*1536 + dir*768 + wq0 + q0] = pk;
      }
      // NOTE: frozen (t >= gL) batches' h is never consumed downstream —
      // their z rows are discarded and enc is only written for t < gL —
      // so no freeze store is needed.
    }
    asm volatile("s_waitcnt vmcnt(0)" ::: "memory");  // h stores ack'd at IC
    __syncthreads();
    if (t < 511){
      if (tid == 0)   // arrive: plain coherent store to private slot
        __hip_atomic_store(barr + slot, t + 1, __ATOMIC_RELAXED, __HIP_MEMORY_SCOPE_AGENT);
      if (wgd == 0 && w == 0){   // per-dir master: poll own dir's 96 slots
        for (;;){
          int v0 = __hip_atomic_load(barr + sb + l, __ATOMIC_RELAXED, __HIP_MEMORY_SCOPE_AGENT);
          int v1 = (l < 32)
            ? __hip_atomic_load(barr + sb + 64 + l, __ATOMIC_RELAXED, __HIP_MEMORY_SCOPE_AGENT)
            : 0x7fffffff;
          if (__all(min(v0, v1) >= t + 1)) break;
          __builtin_amdgcn_s_sleep(1);
        }
        if (l == 0)
          __hip_atomic_store(genp, t + 1, __ATOMIC_RELAXED, __HIP_MEMORY_SCOPE_AGENT);
      }
    }
  }
  // write back registerized c for the next chunk
  cst[ghidx]     = creg[0];
  cst[ghidx + 1] = creg[1];
}

// ------------------------- attention tail ----------------------------------
__global__ void softmax_kernel(const float* __restrict__ scores,
                               const int* __restrict__ nf,
                               float* __restrict__ attn){
  __shared__ float red[4], red2[4];
  int b = blockIdx.x, tid = threadIdx.x;
  int L = nf[b];
  float v0 = (tid       < L) ? scores[b*512 + tid]       : -1e30f;
  float v1 = (tid + 256 < L) ? scores[b*512 + tid + 256] : -1e30f;
  float mx = fmaxf(v0, v1);
  for (int m=1; m<64; m<<=1) mx = fmaxf(mx, __shfl_xor(mx, m));
  if ((tid & 63) == 0) red[tid >> 6] = mx;
  __syncthreads();
  mx = fmaxf(fmaxf(red[0], red[1]), fmaxf(red[2], red[3]));
  float e0 = (tid       < L) ? __expf(v0 - mx) : 0.f;
  float e1 = (tid + 256 < L) ? __expf(v1 - mx) : 0.f;
  float s = e0 + e1;
  for (int m=1; m<64; m<<=1) s += __shfl_xor(s, m);
  if ((tid & 63) == 0) red2[tid >> 6] = s;
  __syncthreads();
  s = red2[0] + red2[1] + red2[2] + red2[3];
  float inv = 1.f / s;
  attn[b*512 + tid]       = e0 * inv;
  attn[b*512 + tid + 256] = e1 * inv;
}

__global__ void context_kernel(const ushort* __restrict__ enc,
                               const float* __restrict__ attn,
                               float* __restrict__ ctx){
  int b = blockIdx.x, tid = threadIdx.x;
  float a6[6] = {0.f,0.f,0.f,0.f,0.f,0.f};
  for (int t=0; t<512; t++){
    float a = attn[b*512 + t];
    if (a != 0.f){
      const ushort* e = enc + ((size_t)b*512 + t)*1536;
      #pragma unroll
      for (int i=0;i<6;i++) a6[i] += a * bf2f(e[tid + i*256]);
    }
  }
  #pragma unroll
  for (int i=0;i<6;i++) ctx[b*1536 + tid + i*256] = a6[i];
}

__global__ void post_kernel(const float* __restrict__ ctx,
                            const float* __restrict__ Wp,
                            const float* __restrict__ bp,
                            float* __restrict__ post){
  int b = blockIdx.x;
  int j = blockIdx.y*256 + threadIdx.x;
  float acc = bp[j];
  const float* c = ctx + b*1536;
  for (int k=0;k<1536;k++) acc += c[k] * Wp[(size_t)k*1536 + j];
  post[b*1536 + j] = acc;
}

__global__ void intents_kernel(const float* __restrict__ post,
                               const float* __restrict__ Wi,
                               const float* __restrict__ bi,
                               float* __restrict__ out){
  int b = blockIdx.x, j = threadIdx.x;
  if (j < 60){
    float acc = bi[j];
    const float* p = post + b*1536;
    for (int k=0;k<1536;k++) acc += p[k] * Wi[k*60 + j];
    out[b*60 + j] = acc;
  }
}

// ------------------------- host side ---------------------------------------
extern "C" void kernel_launch(void* const* d_in, const int* in_sizes, int n_in,
                              void* d_out, int out_size, void* d_ws, size_t ws_size,
                              hipStream_t stream) {
  const float* lat    = (const float*)d_in[0];
  const int*   nf     = (const int*)  d_in[1];
  const float* W_reg  = (const float*)d_in[3];
  const float* b_reg  = (const float*)d_in[4];
  const float* Wi0f   = (const float*)d_in[5];
  const float* Wh0f   = (const float*)d_in[6];
  const float* b0f    = (const float*)d_in[7];
  const float* Wi0b   = (const float*)d_in[8];
  const float* Wh0b   = (const float*)d_in[9];
  const float* b0b    = (const float*)d_in[10];
  const float* Wi1f   = (const float*)d_in[11];
  const float* Wh1f   = (const float*)d_in[12];
  const float* b1f    = (const float*)d_in[13];
  const float* Wi1b   = (const float*)d_in[14];
  const float* Wh1b   = (const float*)d_in[15];
  const float* b1b    = (const float*)d_in[16];
  const float* W_keys = (const float*)d_in[17];
  const float* W_en   = (const float*)d_in[18];
  const float* W_post = (const float*)d_in[19];
  const float* b_post = (const float*)d_in[20];
  const float* W_int  = (const float*)d_in[21];
  const float* b_int  = (const float*)d_in[22];
  float* out = (float*)d_out;

  char* wsp = (char*)d_ws;
  auto alloc = [&](size_t n) -> char* {
    char* p = wsp; wsp += (n + 255) & ~(size_t)255; return p;
  };
  ushort* enc1 = (ushort*)alloc((size_t)MTOT*1536*2);
  ushort* enc2 = (ushort*)alloc((size_t)MTOT*1536*2);
  ushort* wip  = (ushort*)alloc((size_t)2*96*32*1536*2);
  ushort* wh_fh = (ushort*)alloc((size_t)2359296*2);
  ushort* wh_fl = (ushort*)alloc((size_t)2359296*2);
  ushort* wh_bh = (ushort*)alloc((size_t)2359296*2);
  ushort* wh_bl = (ushort*)alloc((size_t)2359296*2);
  float*  bc   = (float*) alloc((size_t)2*3072*4);
  char* state0 = wsp;
  ushort* hstate = (ushort*)alloc((size_t)4*49152*2);   // hi-only: dir x phase
  float*  cstate = (float*) alloc((size_t)2*49152*4);
  int*    barr   = (int*)   alloc(4096);
  size_t state_bytes = (size_t)((char*)wsp - state0);
  // Union region U (25,165,824 B):
  //  - prep phase:   sTh(6291456) | sTl(6291456) | sWc(12582912)
  //  - chunk phase:  xpc = TC*64*6144*2 = 25165824 (whole region)
  //  - attn phase:   sTh | sTl | scores/attn/ctx/postb (13.6 MB total)
  char* U = alloc((size_t)25165824);
  ushort* sTh  = (ushort*)(U);
  ushort* sTl  = (ushort*)(U + 6291456);
  float*  sWc  = (float*) (U + 12582912);
  ushort* xpc  = (ushort*)(U);
  float* scores = (float*)(U + 12582912);
  float* attn   = (float*)(U + 12582912 + 131072);
  float* ctx    = (float*)(U + 12582912 + 262144);
  float* postb  = (float*)(U + 12582912 + 262144 + 393216);
  (void)in_sizes; (void)n_in; (void)out_size; (void)ws_size;

  int state_words = (int)(state_bytes / 4);

  // ---- layer 0 prep: Wc = W_reg @ Wi0{f,b}, pack; Wh0 packs; bias comb ----
  hipLaunchKernelGGL(zero_kernel, dim3(512), dim3(256), 0, stream, (uint32_t*)state0, state_words);
  hipLaunchKernelGGL(transpose_split_kernel, dim3(16,48), dim3(256), 0, stream, Wi0f, sTh, sTl, 1024, 3072);
  hipLaunchKernelGGL((gemm_kernel<0,0>), dim3(8*24), dim3(256), 0, stream,
                     (const void*)W_reg, sTh, sTl, (const float*)nullptr, sWc,
                     (const float*)nullptr, (float*)nullptr, (const int*)nullptr, 1024, 3072, 1024);
  hipLaunchKernelGGL(pack_wi_kernel, dim3(4608), dim3(256), 0, stream, sWc, wip, 1024);
  hipLaunchKernelGGL(transpose_split_kernel, dim3(16,48), dim3(256), 0, stream, Wi0b, sTh, sTl, 1024, 3072);
  hipLaunchKernelGGL((gemm_kernel<0,0>), dim3(8*24), dim3(256), 0, stream,
                     (const void*)W_reg, sTh, sTl, (const float*)nullptr, sWc,
                     (const float*)nullptr, (float*)nullptr, (const int*)nullptr, 1024, 3072, 1024);
  hipLaunchKernelGGL(pack_wi_kernel, dim3(4608), dim3(256), 0, stream, sWc, wip + (size_t)96*32*1024, 1024);
  hipLaunchKernelGGL(whpack_kernel, dim3(9216), dim3(256), 0, stream, Wh0f, wh_fh, wh_fl);
  hipLaunchKernelGGL(whpack_kernel, dim3(9216), dim3(256), 0, stream, Wh0b, wh_bh, wh_bl);
  hipLaunchKernelGGL(bias_comb_kernel, dim3(12,2), dim3(256), 0, stream, b0f, b0b, Wi0f, Wi0b, b_reg, 1024, bc);
  // ---- BiLSTM layer 0: chunked xp (lat fp32, hi-only) + recurrence ----
  for (int c = 0; c < 512/TC; c++){
    int t0 = c*TC;
    hipLaunchKernelGGL((xp_gemm<2>), dim3(16*48), dim3(256), 0, stream,
                       (const void*)lat, wip, nf, t0, xpc, 1024);
    hipLaunchKernelGGL(recur_fused, dim3(192), dim3(256), 0, stream,
                       xpc, wh_fh, wh_fl, wh_bh, wh_bl, bc,
                       enc1, nf, hstate, cstate, barr, t0, t0 + TC);
  }
  // ---- layer 1 prep ----
  hipLaunchKernelGGL(zero_kernel, dim3(512), dim3(256), 0, stream, (uint32_t*)state0, state_words);
  hipLaunchKernelGGL(pack_wi_kernel, dim3(4608), dim3(256), 0, stream, Wi1f, wip, 1536);
  hipLaunchKernelGGL(pack_wi_kernel, dim3(4608), dim3(256), 0, stream, Wi1b, wip + (size_t)96*32*1536, 1536);
  hipLaunchKernelGGL(whpack_kernel, dim3(9216), dim3(256), 0, stream, Wh1f, wh_fh, wh_fl);
  hipLaunchKernelGGL(whpack_kernel, dim3(9216), dim3(256), 0, stream, Wh1b, wh_bh, wh_bl);
  hipLaunchKernelGGL(bias_comb_kernel, dim3(12,2), dim3(256), 0, stream, b1f, b1b,
                     (const float*)nullptr, (const float*)nullptr, b_reg, 0, bc);
  // ---- BiLSTM layer 1: chunked xp (enc1 bf16) + recurrence ----
  for (int c = 0; c < 512/TC; c++){
    int t0 = c*TC;
    hipLaunchKernelGGL((xp_gemm<1>), dim3(16*48), dim3(256), 0, stream,
                       (const void*)enc1, wip, nf, t0, xpc, 1536);
    hipLaunchKernelGGL(recur_fused, dim3(192), dim3(256), 0, stream,
                       xpc, wh_fh, wh_fl, wh_bh, wh_bl, bc,
                       enc2, nf, hstate, cstate, barr, t0, t0 + TC);
  }
  // ---- attention: scores = sum_col tanh(enc2@Wk)*We ----
  hipLaunchKernelGGL(zero_kernel, dim3(128), dim3(256), 0, stream, (uint32_t*)scores, MTOT);
  hipLaunchKernelGGL(transpose_split_kernel, dim3(24,24), dim3(256), 0, stream, W_keys, sTh, sTl, 1536, 1536);
  hipLaunchKernelGGL((gemm_kernel<2,1>), dim3(256*12), dim3(256), 0, stream,
                     (const void*)enc2, sTh, sTl, (const float*)nullptr, (float*)nullptr,
                     W_en, scores, nf, MTOT, 1536, 1536);
  hipLaunchKernelGGL(softmax_kernel, dim3(64), dim3(256), 0, stream, scores, nf, attn);
  hipLaunchKernelGGL(context_kernel, dim3(64), dim3(256), 0, stream, enc2, attn, ctx);
  hipLaunchKernelGGL(post_kernel, dim3(64,6), dim3(256), 0, stream, ctx, W_post, b_post, postb);
  hipLaunchKernelGGL(intents_kernel, dim3(64), dim3(64), 0, stream, postb, W_int, b_int, out);
}